// Round 13
// baseline (189.060 us; speedup 1.0000x reference)
//
#include <hip/hip_runtime.h>

#define NROWS 65536
#define KDIM  512
constexpr float BN_EPS = 1e-5f;

using short8 = __attribute__((ext_vector_type(8))) short;
using f32x4  = __attribute__((ext_vector_type(4))) float;

#define BM 64

// async global->LDS, 16B per lane
__device__ __forceinline__ void gload_lds16(const float* g, float* l) {
  __builtin_amdgcn_global_load_lds(
      (const __attribute__((address_space(1))) void*)g,
      (__attribute__((address_space(3))) void*)l, 16, 0, 0);
}

// RNE fp32 -> bf16 pack of 8 floats
__device__ __forceinline__ short8 cvthi8(const float4& a, const float4& b) {
  const float e[8] = {a.x, a.y, a.z, a.w, b.x, b.y, b.z, b.w};
  short8 h;
  #pragma unroll
  for (int i = 0; i < 8; ++i) {
    unsigned u = __float_as_uint(e[i]);
    u += 0x7FFFu + ((u >> 16) & 1u);
    h[i] = (short)(u >> 16);
  }
  return h;
}

// ---------------- prep: C1 -> fragment-tiled bf16 (RNE) ----------------
// entry e = kg*512 + col holds C1[kg*8 + i][col], i=0..7 (one B-fragment).
// k-tile kt's 32 KB block (entries kt*2048..+2047) is exactly what a
// workgroup needs for that kt, in linear order -> pure DMA staging.
__global__ __launch_bounds__(256)
void prep_c1(const float* __restrict__ C1, short8* __restrict__ c1tH) {
  const int e   = blockIdx.x * 256 + threadIdx.x;   // 0..32767
  const int col = e & 511;
  const int kg  = e >> 9;
  short8 hi;
  #pragma unroll
  for (int i = 0; i < 8; ++i) {
    const float x = C1[(size_t)(kg * 8 + i) * KDIM + col];   // coalesced
    unsigned u = __float_as_uint(x);
    u += 0x7FFFu + ((u >> 16) & 1u);
    hi[i] = (short)(u >> 16);
  }
  c1tH[e] = hi;
}

// ---------------- quad: pipelined streamed A + async-LDS-staged B ----------------
// quad[n] = x_n^T C1 x_n (1-pass bf16 MFMA), fused column stats.
// 8 waves = 2 row-groups x 4 col-groups (wave tile 32 rows x 128 cols).
// Iteration kt: FIRST issue A(kt+1) global loads and the kt+1 B-DMA
// (global_load_lds, double-buffered), THEN compute kt from registers/LDS
// that completed at the kt-1 barrier. vmcnt FIFO ordering means the cvt
// for kt needs no wait (its loads predate the last barrier), and the
// freshly-issued loads have the whole compute phase to land before the
// end-of-kt barrier drain. A raw regs ping-pong on kt&1 (static after
// full unroll).
__global__ __launch_bounds__(512)
void quad_kernel(const float* __restrict__ X, const short8* __restrict__ c1tH,
                 float* __restrict__ quad,
                 float* __restrict__ colS1, float* __restrict__ colS2,
                 float* __restrict__ colS3, double* __restrict__ qsums) {
  __shared__ short8 Bs[2][2048];      // 2 x 32 KB
  __shared__ float qPart[4][BM];
  __shared__ float qLds[BM];

  const int tid  = threadIdx.x;
  const int lane = tid & 63;
  const int w    = tid >> 6;          // wave 0..7
  const int wr   = w >> 2;            // row-group (0..1): rows wr*32..+31
  const int wc   = w & 3;             // col-group (0..3): cols wc*128..+127
  const int g    = lane >> 4;         // k-group 0..3
  const int lr   = lane & 15;
  const int r0   = blockIdx.x * BM;

#define STAGE(buf, kt)                                                     \
  {                                                                        \
    _Pragma("unroll")                                                      \
    for (int s = 0; s < 4; ++s)                                            \
      gload_lds16((const float*)(c1tH + (kt) * 2048 + s * 512 + tid),      \
                  (float*)&Bs[buf][s * 512 + tid]);                        \
  }

#define LOADA(kt, dst)                                                     \
  {                                                                        \
    dst[0] = *(const float4*)(xpA0 + (kt) * 32);                           \
    dst[1] = *(const float4*)(xpA0 + (kt) * 32 + 4);                       \
    dst[2] = *(const float4*)(xpA1 + (kt) * 32);                           \
    dst[3] = *(const float4*)(xpA1 + (kt) * 32 + 4);                       \
  }

  // A stream bases: lane (g,lr) reads rows wr*32+rf*16+lr, k = kt*32+g*8..+7
  const float* xpA0 = X + (size_t)(r0 + wr * 32 + lr) * KDIM + g * 8;
  const float* xpA1 = xpA0 + 16 * KDIM;

  f32x4 acc[2][8];
  #pragma unroll
  for (int rf = 0; rf < 2; ++rf)
    #pragma unroll
    for (int cf = 0; cf < 8; ++cf)
      acc[rf][cf] = (f32x4){0.f, 0.f, 0.f, 0.f};

  float4 ar[2][4];                    // ping-pong raw-A (indices static after unroll)

  // prologue: A(0) + B-DMA(0); the barrier drain completes both
  LOADA(0, ar[0]);
  STAGE(0, 0);
  __syncthreads();

  int cur = 0;
  #pragma unroll
  for (int kt = 0; kt < 16; ++kt) {
    // ---- issue NEXT iteration's loads first (land during this kt's compute) ----
    if (kt < 15) {
      LOADA(kt + 1, ar[(kt + 1) & 1]);
      STAGE(cur ^ 1, kt + 1);
    }
    // ---- compute kt: inputs completed at the previous barrier (no waits) ----
    const short8 A0 = cvthi8(ar[kt & 1][0], ar[kt & 1][1]);
    const short8 A1 = cvthi8(ar[kt & 1][2], ar[kt & 1][3]);

    const int fb = g * 512 + wc * 128 + lr;
    {
      const short8 b0 = Bs[cur][fb];
      const short8 b1 = Bs[cur][fb + 16];
      const short8 b2 = Bs[cur][fb + 32];
      const short8 b3 = Bs[cur][fb + 48];
      acc[0][0] = __builtin_amdgcn_mfma_f32_16x16x32_bf16(A0, b0, acc[0][0], 0, 0, 0);
      acc[1][0] = __builtin_amdgcn_mfma_f32_16x16x32_bf16(A1, b0, acc[1][0], 0, 0, 0);
      acc[0][1] = __builtin_amdgcn_mfma_f32_16x16x32_bf16(A0, b1, acc[0][1], 0, 0, 0);
      acc[1][1] = __builtin_amdgcn_mfma_f32_16x16x32_bf16(A1, b1, acc[1][1], 0, 0, 0);
      acc[0][2] = __builtin_amdgcn_mfma_f32_16x16x32_bf16(A0, b2, acc[0][2], 0, 0, 0);
      acc[1][2] = __builtin_amdgcn_mfma_f32_16x16x32_bf16(A1, b2, acc[1][2], 0, 0, 0);
      acc[0][3] = __builtin_amdgcn_mfma_f32_16x16x32_bf16(A0, b3, acc[0][3], 0, 0, 0);
      acc[1][3] = __builtin_amdgcn_mfma_f32_16x16x32_bf16(A1, b3, acc[1][3], 0, 0, 0);
    }
    {
      const short8 b4 = Bs[cur][fb + 64];
      const short8 b5 = Bs[cur][fb + 80];
      const short8 b6 = Bs[cur][fb + 96];
      const short8 b7 = Bs[cur][fb + 112];
      acc[0][4] = __builtin_amdgcn_mfma_f32_16x16x32_bf16(A0, b4, acc[0][4], 0, 0, 0);
      acc[1][4] = __builtin_amdgcn_mfma_f32_16x16x32_bf16(A1, b4, acc[1][4], 0, 0, 0);
      acc[0][5] = __builtin_amdgcn_mfma_f32_16x16x32_bf16(A0, b5, acc[0][5], 0, 0, 0);
      acc[1][5] = __builtin_amdgcn_mfma_f32_16x16x32_bf16(A1, b5, acc[1][5], 0, 0, 0);
      acc[0][6] = __builtin_amdgcn_mfma_f32_16x16x32_bf16(A0, b6, acc[0][6], 0, 0, 0);
      acc[1][6] = __builtin_amdgcn_mfma_f32_16x16x32_bf16(A1, b6, acc[1][6], 0, 0, 0);
      acc[0][7] = __builtin_amdgcn_mfma_f32_16x16x32_bf16(A0, b7, acc[0][7], 0, 0, 0);
      acc[1][7] = __builtin_amdgcn_mfma_f32_16x16x32_bf16(A1, b7, acc[1][7], 0, 0, 0);
    }
    __syncthreads();                  // drains the (mostly-landed) prefetch
    cur ^= 1;
  }
#undef STAGE
#undef LOADA

  // ---- epilogue: row-dot against X for this wave's 128-col slice ----
  #pragma unroll
  for (int rf = 0; rf < 2; ++rf)
    #pragma unroll
    for (int p = 0; p < 4; ++p) {
      const int row = wr * 32 + rf * 16 + g * 4 + p;
      const float* xr = X + (size_t)(r0 + row) * KDIM + wc * 128;
      float s = 0.f;
      #pragma unroll
      for (int cf = 0; cf < 8; ++cf)
        s += acc[rf][cf][p] * xr[cf * 16 + lr];
      s += __shfl_xor(s, 1, 64);
      s += __shfl_xor(s, 2, 64);
      s += __shfl_xor(s, 4, 64);
      s += __shfl_xor(s, 8, 64);
      if (lr == 0) qPart[wc][row] = s;
    }
  __syncthreads();
  if (tid < BM) {
    const float q = qPart[0][tid] + qPart[1][tid] + qPart[2][tid] + qPart[3][tid];
    quad[r0 + tid] = q;
    qLds[tid] = q;
  }
  __syncthreads();
  // ---- fused column stats over the (cache-hot) X panel: 1 col per thread ----
  {
    float s1 = 0.f, s2 = 0.f, s3 = 0.f;
    for (int r = 0; r < BM; ++r) {
      const float q = qLds[r];
      const float x = X[(size_t)(r0 + r) * KDIM + tid];
      s1 += x; s2 += x * x; s3 += q * x;
    }
    atomicAdd(&colS1[tid], s1);
    atomicAdd(&colS2[tid], s2);
    atomicAdd(&colS3[tid], s3);
  }
  if (tid < BM) {   // one full wave: reduce q, q^2 across 64 lanes
    double q = (double)qLds[tid];
    double q2 = q * q;
    #pragma unroll
    for (int m = 1; m < 64; m <<= 1) {
      q  += __shfl_xor(q,  m, 64);
      q2 += __shfl_xor(q2, m, 64);
    }
    if (tid == 0) { atomicAdd(&qsums[0], q); atomicAdd(&qsums[1], q2); }
  }
}

// ---------------- finalize per-feature mean / inv_std ----------------
__global__ void finalize_kernel(const float* __restrict__ colS1, const float* __restrict__ colS2,
                                const float* __restrict__ colS3, const double* __restrict__ qsums,
                                const float* __restrict__ C2, const float* __restrict__ C3,
                                float* __restrict__ mean, float* __restrict__ inv_std) {
  const int k = blockIdx.x * blockDim.x + threadIdx.x;
  if (k >= KDIM) return;
  const double invN = 1.0 / (double)NROWS;
  const double meanQ = qsums[0] * invN;
  const double varQ  = qsums[1] * invN - meanQ * meanQ;
  const float meanX = colS1[k] * (float)invN;
  const float varX  = colS2[k] * (float)invN - meanX * meanX;
  const float covQX = colS3[k] * (float)invN - (float)meanQ * meanX;
  const float c2 = C2[k];
  const float c3 = C3[0];
  const float m = (float)meanQ + c2 * meanX + c3;
  const float v = (float)varQ + c2 * c2 * varX + 2.0f * c2 * covQX;
  mean[k] = m;
  inv_std[k] = 1.0f / sqrtf(v + BN_EPS);
}

// ---------------- normalize + write ----------------
__global__ __launch_bounds__(256)
void normalize_kernel(const float* __restrict__ X, const float* __restrict__ quad,
                      const float* __restrict__ C2, const float* __restrict__ C3,
                      const float* __restrict__ mean, const float* __restrict__ inv_std,
                      float* __restrict__ out) {
  const int idx = blockIdx.x * blockDim.x + threadIdx.x;  // float4 index
  const int n = idx >> 7;
  const int j4 = idx & 127;
  const float q = quad[n];
  const float c3 = C3[0];
  const float4 x  = *(const float4*)&X[(size_t)idx * 4];
  const float4 c2 = *(const float4*)&C2[j4 * 4];
  const float4 m  = *(const float4*)&mean[j4 * 4];
  const float4 iv = *(const float4*)&inv_std[j4 * 4];
  float4 o;
  o.x = (q + c2.x * x.x + c3 - m.x) * iv.x;
  o.y = (q + c2.y * x.y + c3 - m.y) * iv.y;
  o.z = (q + c2.z * x.z + c3 - m.z) * iv.z;
  o.w = (q + c2.w * x.w + c3 - m.w) * iv.w;
  *(float4*)&out[(size_t)idx * 4] = o;
}

extern "C" void kernel_launch(void* const* d_in, const int* in_sizes, int n_in,
                              void* d_out, int out_size, void* d_ws, size_t ws_size,
                              hipStream_t stream) {
  const float* X  = (const float*)d_in[0];
  const float* C1 = (const float*)d_in[1];
  const float* C2 = (const float*)d_in[2];
  const float* C3 = (const float*)d_in[3];
  float* out = (float*)d_out;

  char* ws = (char*)d_ws;
  float*  quad    = (float*)ws;                                        // 256 KB
  float*  colS1   = (float*)(ws + (size_t)NROWS * 4);                  // K
  float*  colS2   = colS1 + KDIM;
  float*  colS3   = colS2 + KDIM;
  double* qsums   = (double*)(ws + (size_t)NROWS * 4 + 3 * KDIM * 4);  // 2 doubles
  float*  mean    = (float*)(ws + (size_t)NROWS * 4 + 3 * KDIM * 4 + 16);
  float*  inv_std = mean + KDIM;
  short8* c1tH    = (short8*)(ws + 276480);                            // 512 KB (16B aligned)

  hipMemsetAsync(colS1, 0, 3 * KDIM * 4 + 16, stream);

  prep_c1<<<128, 256, 0, stream>>>(C1, c1tH);
  quad_kernel<<<NROWS / BM, 512, 0, stream>>>(X, c1tH, quad,
                                              colS1, colS2, colS3, qsums);
  finalize_kernel<<<2, 256, 0, stream>>>(colS1, colS2, colS3, qsums, C2, C3, mean, inv_std);
  normalize_kernel<<<(NROWS * (KDIM / 4)) / 256, 256, 0, stream>>>(
      X, quad, C2, C3, mean, inv_std, out);
}

// Round 14
// 157.566 us; speedup vs baseline: 1.1999x; 1.1999x over previous
//
#include <hip/hip_runtime.h>

#define NROWS 65536
#define KDIM  512
constexpr float BN_EPS = 1e-5f;

using short8 = __attribute__((ext_vector_type(8))) short;
using f32x4  = __attribute__((ext_vector_type(4))) float;

#define BM 64

// async global->LDS, 16B per lane
__device__ __forceinline__ void gload_lds16(const void* g, void* l) {
  __builtin_amdgcn_global_load_lds(
      (const __attribute__((address_space(1))) void*)g,
      (__attribute__((address_space(3))) void*)l, 16, 0, 0);
}

// RNE fp32 -> bf16 pack of 8 floats
__device__ __forceinline__ short8 cvthi8(const float4& a, const float4& b) {
  const float e[8] = {a.x, a.y, a.z, a.w, b.x, b.y, b.z, b.w};
  short8 h;
  #pragma unroll
  for (int i = 0; i < 8; ++i) {
    unsigned u = __float_as_uint(e[i]);
    u += 0x7FFFu + ((u >> 16) & 1u);
    h[i] = (short)(u >> 16);
  }
  return h;
}

// ---------------- prep: C1 -> fragment-tiled bf16 (RNE) ----------------
// entry e = kg*512 + col holds C1[kg*8 + i][col], i=0..7 (one B-fragment).
__global__ __launch_bounds__(256)
void prep_c1(const float* __restrict__ C1, short8* __restrict__ c1tH) {
  const int e   = blockIdx.x * 256 + threadIdx.x;   // 0..32767
  const int col = e & 511;
  const int kg  = e >> 9;
  short8 hi;
  #pragma unroll
  for (int i = 0; i < 8; ++i) {
    const float x = C1[(size_t)(kg * 8 + i) * KDIM + col];   // coalesced
    unsigned u = __float_as_uint(x);
    u += 0x7FFFu + ((u >> 16) & 1u);
    hi[i] = (short)(u >> 16);
  }
  c1tH[e] = hi;
}

// ---------------- prep: X -> fragment-tiled bf16 (RNE) ----------------
// Per 64-row panel b: entry (kt*4+g)*64 + row holds X[b*64+row][kt*32+g*8..+7].
// Per (b,kt) the 256 entries (4 KB) are contiguous -> linear DMA in quad.
__global__ __launch_bounds__(512)
void prep_x(const float* __restrict__ X, short8* __restrict__ xbf) {
  const int b   = blockIdx.x;
  const int tid = threadIdx.x;
  const int row = tid >> 3;           // 0..63
  const int seg = tid & 7;            // 64-k segment
  const float* xp = X + ((size_t)b * 64 + row) * KDIM + seg * 64;
  short8* dst = xbf + (size_t)b * 4096;
  #pragma unroll
  for (int j = 0; j < 8; ++j) {
    const float4 a = *(const float4*)(xp + j * 8);
    const float4 c = *(const float4*)(xp + j * 8 + 4);
    const int kt = seg * 2 + (j >> 2);
    const int g  = j & 3;
    dst[(kt * 4 + g) * 64 + row] = cvthi8(a, c);   // 8-lane groups write 128B contig
  }
}

// ---------------- quad: pure LDS+MFMA main loop (m97 shape) ----------------
// quad[n] = x_n^T C1 x_n (1-pass bf16 MFMA), fused column stats.
// 8 waves = 2 row-groups x 4 col-groups (wave tile 32 rows x 128 cols).
// Per kt: issue next kt's A-DMA (4 KB) + B-DMA (32 KB) via global_load_lds
// (no VGPR destinations), then compute current kt from LDS only:
// 10 conflict-free ds_read_b128 + 16 MFMA per wave. No cvt, no global
// VGPR loads, one barrier per kt. A was pre-converted by prep_x.
__global__ __launch_bounds__(512)
void quad_kernel(const float* __restrict__ X, const short8* __restrict__ xbf,
                 const short8* __restrict__ c1tH,
                 float* __restrict__ quad,
                 float* __restrict__ colS1, float* __restrict__ colS2,
                 float* __restrict__ colS3, double* __restrict__ qsums) {
  __shared__ short8 Bs[2][2048];      // 2 x 32 KB
  __shared__ short8 As[2][256];       // 2 x 4 KB
  __shared__ float qPart[4][BM];
  __shared__ float qLds[BM];

  const int tid  = threadIdx.x;
  const int lane = tid & 63;
  const int w    = tid >> 6;          // wave 0..7
  const int wr   = w >> 2;            // row-group (0..1): rows wr*32..+31
  const int wc   = w & 3;             // col-group (0..3): cols wc*128..+127
  const int g    = lane >> 4;         // k-group 0..3
  const int lr   = lane & 15;
  const int r0   = blockIdx.x * BM;
  const short8* xbfb = xbf + (size_t)blockIdx.x * 4096;

#define STAGE_B(buf, kt)                                                   \
  {                                                                        \
    _Pragma("unroll")                                                      \
    for (int s = 0; s < 4; ++s)                                            \
      gload_lds16(c1tH + (kt) * 2048 + s * 512 + tid,                      \
                  &Bs[buf][s * 512 + tid]);                                \
  }
#define STAGE_A(buf, kt)                                                   \
  {                                                                        \
    if (tid < 256) gload_lds16(xbfb + (kt) * 256 + tid, &As[buf][tid]);    \
  }

  f32x4 acc[2][8];
  #pragma unroll
  for (int rf = 0; rf < 2; ++rf)
    #pragma unroll
    for (int cf = 0; cf < 8; ++cf)
      acc[rf][cf] = (f32x4){0.f, 0.f, 0.f, 0.f};

  STAGE_B(0, 0);
  STAGE_A(0, 0);
  __syncthreads();

  int cur = 0;
  #pragma unroll
  for (int kt = 0; kt < 16; ++kt) {
    if (kt < 15) {                    // prefetch next kt (no VGPR destinations)
      STAGE_B(cur ^ 1, kt + 1);
      STAGE_A(cur ^ 1, kt + 1);
    }
    // A fragments from LDS (256B-contiguous per 16-lane group)
    const int fa = g * 64 + wr * 32 + lr;
    const short8 A0 = As[cur][fa];
    const short8 A1 = As[cur][fa + 16];
    // B fragments from LDS
    const int fb = g * 512 + wc * 128 + lr;
    {
      const short8 b0 = Bs[cur][fb];
      const short8 b1 = Bs[cur][fb + 16];
      const short8 b2 = Bs[cur][fb + 32];
      const short8 b3 = Bs[cur][fb + 48];
      acc[0][0] = __builtin_amdgcn_mfma_f32_16x16x32_bf16(A0, b0, acc[0][0], 0, 0, 0);
      acc[1][0] = __builtin_amdgcn_mfma_f32_16x16x32_bf16(A1, b0, acc[1][0], 0, 0, 0);
      acc[0][1] = __builtin_amdgcn_mfma_f32_16x16x32_bf16(A0, b1, acc[0][1], 0, 0, 0);
      acc[1][1] = __builtin_amdgcn_mfma_f32_16x16x32_bf16(A1, b1, acc[1][1], 0, 0, 0);
      acc[0][2] = __builtin_amdgcn_mfma_f32_16x16x32_bf16(A0, b2, acc[0][2], 0, 0, 0);
      acc[1][2] = __builtin_amdgcn_mfma_f32_16x16x32_bf16(A1, b2, acc[1][2], 0, 0, 0);
      acc[0][3] = __builtin_amdgcn_mfma_f32_16x16x32_bf16(A0, b3, acc[0][3], 0, 0, 0);
      acc[1][3] = __builtin_amdgcn_mfma_f32_16x16x32_bf16(A1, b3, acc[1][3], 0, 0, 0);
    }
    {
      const short8 b4 = Bs[cur][fb + 64];
      const short8 b5 = Bs[cur][fb + 80];
      const short8 b6 = Bs[cur][fb + 96];
      const short8 b7 = Bs[cur][fb + 112];
      acc[0][4] = __builtin_amdgcn_mfma_f32_16x16x32_bf16(A0, b4, acc[0][4], 0, 0, 0);
      acc[1][4] = __builtin_amdgcn_mfma_f32_16x16x32_bf16(A1, b4, acc[1][4], 0, 0, 0);
      acc[0][5] = __builtin_amdgcn_mfma_f32_16x16x32_bf16(A0, b5, acc[0][5], 0, 0, 0);
      acc[1][5] = __builtin_amdgcn_mfma_f32_16x16x32_bf16(A1, b5, acc[1][5], 0, 0, 0);
      acc[0][6] = __builtin_amdgcn_mfma_f32_16x16x32_bf16(A0, b6, acc[0][6], 0, 0, 0);
      acc[1][6] = __builtin_amdgcn_mfma_f32_16x16x32_bf16(A1, b6, acc[1][6], 0, 0, 0);
      acc[0][7] = __builtin_amdgcn_mfma_f32_16x16x32_bf16(A0, b7, acc[0][7], 0, 0, 0);
      acc[1][7] = __builtin_amdgcn_mfma_f32_16x16x32_bf16(A1, b7, acc[1][7], 0, 0, 0);
    }
    __syncthreads();                  // prefetch had the whole compute phase to land
    cur ^= 1;
  }
#undef STAGE_B
#undef STAGE_A

  // ---- epilogue: row-dot against X for this wave's 128-col slice ----
  #pragma unroll
  for (int rf = 0; rf < 2; ++rf)
    #pragma unroll
    for (int p = 0; p < 4; ++p) {
      const int row = wr * 32 + rf * 16 + g * 4 + p;
      const float* xr = X + (size_t)(r0 + row) * KDIM + wc * 128;
      float s = 0.f;
      #pragma unroll
      for (int cf = 0; cf < 8; ++cf)
        s += acc[rf][cf][p] * xr[cf * 16 + lr];
      s += __shfl_xor(s, 1, 64);
      s += __shfl_xor(s, 2, 64);
      s += __shfl_xor(s, 4, 64);
      s += __shfl_xor(s, 8, 64);
      if (lr == 0) qPart[wc][row] = s;
    }
  __syncthreads();
  if (tid < BM) {
    const float q = qPart[0][tid] + qPart[1][tid] + qPart[2][tid] + qPart[3][tid];
    quad[r0 + tid] = q;
    qLds[tid] = q;
  }
  __syncthreads();
  // ---- fused column stats over the (cache-hot) X panel: 1 col per thread ----
  {
    float s1 = 0.f, s2 = 0.f, s3 = 0.f;
    for (int r = 0; r < BM; ++r) {
      const float q = qLds[r];
      const float x = X[(size_t)(r0 + r) * KDIM + tid];
      s1 += x; s2 += x * x; s3 += q * x;
    }
    atomicAdd(&colS1[tid], s1);
    atomicAdd(&colS2[tid], s2);
    atomicAdd(&colS3[tid], s3);
  }
  if (tid < BM) {   // one full wave: reduce q, q^2 across 64 lanes
    double q = (double)qLds[tid];
    double q2 = q * q;
    #pragma unroll
    for (int m = 1; m < 64; m <<= 1) {
      q  += __shfl_xor(q,  m, 64);
      q2 += __shfl_xor(q2, m, 64);
    }
    if (tid == 0) { atomicAdd(&qsums[0], q); atomicAdd(&qsums[1], q2); }
  }
}

// ---------------- finalize per-feature mean / inv_std ----------------
__global__ void finalize_kernel(const float* __restrict__ colS1, const float* __restrict__ colS2,
                                const float* __restrict__ colS3, const double* __restrict__ qsums,
                                const float* __restrict__ C2, const float* __restrict__ C3,
                                float* __restrict__ mean, float* __restrict__ inv_std) {
  const int k = blockIdx.x * blockDim.x + threadIdx.x;
  if (k >= KDIM) return;
  const double invN = 1.0 / (double)NROWS;
  const double meanQ = qsums[0] * invN;
  const double varQ  = qsums[1] * invN - meanQ * meanQ;
  const float meanX = colS1[k] * (float)invN;
  const float varX  = colS2[k] * (float)invN - meanX * meanX;
  const float covQX = colS3[k] * (float)invN - (float)meanQ * meanX;
  const float c2 = C2[k];
  const float c3 = C3[0];
  const float m = (float)meanQ + c2 * meanX + c3;
  const float v = (float)varQ + c2 * c2 * varX + 2.0f * c2 * covQX;
  mean[k] = m;
  inv_std[k] = 1.0f / sqrtf(v + BN_EPS);
}

// ---------------- normalize + write ----------------
__global__ __launch_bounds__(256)
void normalize_kernel(const float* __restrict__ X, const float* __restrict__ quad,
                      const float* __restrict__ C2, const float* __restrict__ C3,
                      const float* __restrict__ mean, const float* __restrict__ inv_std,
                      float* __restrict__ out) {
  const int idx = blockIdx.x * blockDim.x + threadIdx.x;  // float4 index
  const int n = idx >> 7;
  const int j4 = idx & 127;
  const float q = quad[n];
  const float c3 = C3[0];
  const float4 x  = *(const float4*)&X[(size_t)idx * 4];
  const float4 c2 = *(const float4*)&C2[j4 * 4];
  const float4 m  = *(const float4*)&mean[j4 * 4];
  const float4 iv = *(const float4*)&inv_std[j4 * 4];
  float4 o;
  o.x = (q + c2.x * x.x + c3 - m.x) * iv.x;
  o.y = (q + c2.y * x.y + c3 - m.y) * iv.y;
  o.z = (q + c2.z * x.z + c3 - m.z) * iv.z;
  o.w = (q + c2.w * x.w + c3 - m.w) * iv.w;
  *(float4*)&out[(size_t)idx * 4] = o;
}

extern "C" void kernel_launch(void* const* d_in, const int* in_sizes, int n_in,
                              void* d_out, int out_size, void* d_ws, size_t ws_size,
                              hipStream_t stream) {
  const float* X  = (const float*)d_in[0];
  const float* C1 = (const float*)d_in[1];
  const float* C2 = (const float*)d_in[2];
  const float* C3 = (const float*)d_in[3];
  float* out = (float*)d_out;

  char* ws = (char*)d_ws;
  float*  quad    = (float*)ws;                                        // 256 KB
  float*  colS1   = (float*)(ws + (size_t)NROWS * 4);                  // K
  float*  colS2   = colS1 + KDIM;
  float*  colS3   = colS2 + KDIM;
  double* qsums   = (double*)(ws + (size_t)NROWS * 4 + 3 * KDIM * 4);  // 2 doubles
  float*  mean    = (float*)(ws + (size_t)NROWS * 4 + 3 * KDIM * 4 + 16);
  float*  inv_std = mean + KDIM;
  short8* c1tH    = (short8*)(ws + 276480);                            // 512 KB (16B aligned)

  // Xbf (64 MB, fragment-tiled) lives in the FIRST HALF OF d_out: quad
  // finishes reading it before normalize_kernel overwrites all of d_out,
  // and normalize never reads xbf. Deterministic, no extra workspace.
  short8* xbf = (short8*)d_out;

  hipMemsetAsync(colS1, 0, 3 * KDIM * 4 + 16, stream);

  prep_c1<<<128, 256, 0, stream>>>(C1, c1tH);
  prep_x<<<NROWS / 64, 512, 0, stream>>>(X, xbf);
  quad_kernel<<<NROWS / BM, 512, 0, stream>>>(X, xbf, c1tH, quad,
                                              colS1, colS2, colS3, qsums);
  finalize_kernel<<<2, 256, 0, stream>>>(colS1, colS2, colS3, qsums, C2, C3, mean, inv_std);
  normalize_kernel<<<(NROWS * (KDIM / 4)) / 256, 256, 0, stream>>>(
      X, quad, C2, C3, mean, inv_std, out);
}

// Round 15
// 147.961 us; speedup vs baseline: 1.2778x; 1.0649x over previous
//
#include <hip/hip_runtime.h>

#define NROWS 65536
#define KDIM  512
constexpr float BN_EPS = 1e-5f;

using short8 = __attribute__((ext_vector_type(8))) short;
using f32x4  = __attribute__((ext_vector_type(4))) float;

#define BM 64

// async global->LDS, 16B per lane
__device__ __forceinline__ void gload_lds16(const void* g, void* l) {
  __builtin_amdgcn_global_load_lds(
      (const __attribute__((address_space(1))) void*)g,
      (__attribute__((address_space(3))) void*)l, 16, 0, 0);
}

// RNE fp32 -> bf16: convert 4 floats, store as 8 bytes (ds_write_b64)
__device__ __forceinline__ void cvtstore4(const float4 a, void* dst) {
  unsigned u0 = __float_as_uint(a.x); u0 += 0x7FFFu + ((u0 >> 16) & 1u);
  unsigned u1 = __float_as_uint(a.y); u1 += 0x7FFFu + ((u1 >> 16) & 1u);
  unsigned u2 = __float_as_uint(a.z); u2 += 0x7FFFu + ((u2 >> 16) & 1u);
  unsigned u3 = __float_as_uint(a.w); u3 += 0x7FFFu + ((u3 >> 16) & 1u);
  int2 p;
  p.x = (int)((u0 >> 16) | (u1 & 0xFFFF0000u));
  p.y = (int)((u2 >> 16) | (u3 & 0xFFFF0000u));
  *(int2*)dst = p;
}

// ---------------- prep: C1 -> fragment-tiled bf16 (RNE) ----------------
// entry e = kg*512 + col holds C1[kg*8 + i][col], i=0..7 (one B-fragment).
__global__ __launch_bounds__(256)
void prep_c1(const float* __restrict__ C1, short8* __restrict__ c1tH) {
  const int e   = blockIdx.x * 256 + threadIdx.x;   // 0..32767
  const int col = e & 511;
  const int kg  = e >> 9;
  short8 hi;
  #pragma unroll
  for (int i = 0; i < 8; ++i) {
    const float x = C1[(size_t)(kg * 8 + i) * KDIM + col];   // coalesced
    unsigned u = __float_as_uint(x);
    u += 0x7FFFu + ((u >> 16) & 1u);
    hi[i] = (short)(u >> 16);
  }
  c1tH[e] = hi;
}

// ---------------- quad: pure LDS+MFMA loop, A reg-staged in-loop ----------------
// quad[n] = x_n^T C1 x_n (1-pass bf16 MFMA), fused column stats.
// 8 waves = 2 row-groups x 4 col-groups (wave tile 32 rows x 128 cols).
// Per kt phase: (top) issue 1 coalesced float4 X-load per thread (A tile
// for kt+1) + the 32 KB B-DMA (global_load_lds, dbuf); (middle) compute kt
// purely from LDS (10 conflict-free ds_read_b128 + 16 MFMA per wave);
// (late) cvt the landed X float4 -> bf16, one ds_write_b64 into As[buf^1].
// FIFO vmcnt => the cvt's wait is vmcnt(4), leaving the B-DMAs in flight.
// prep_x is gone: X's fp32->bf16 conversion rides inside the phase.
__global__ __launch_bounds__(512)
void quad_kernel(const float* __restrict__ X, const short8* __restrict__ c1tH,
                 float* __restrict__ quad,
                 float* __restrict__ colS1, float* __restrict__ colS2,
                 float* __restrict__ colS3, double* __restrict__ qsums) {
  __shared__ short8 Bs[2][2048];      // 2 x 32 KB
  __shared__ short8 As[2][256];       // 2 x 4 KB  (entry g*64+row = X[row][kt*32+g*8..+7])
  __shared__ float qPart[4][BM];
  __shared__ float qLds[BM];

  const int tid  = threadIdx.x;
  const int lane = tid & 63;
  const int w    = tid >> 6;          // wave 0..7
  const int wr   = w >> 2;            // row-group (0..1): rows wr*32..+31
  const int wc   = w & 3;             // col-group (0..3): cols wc*128..+127
  const int g    = lane >> 4;         // k-group 0..3
  const int lr   = lane & 15;
  const int r0   = blockIdx.x * BM;

  // ---- A staging assignment: thread -> (row, float4-segment) ----
  const int sr   = tid >> 3;          // row 0..63
  const int sseg = tid & 7;           // 4-float segment 0..7 of the 32-k slice
  const float* xsrc = X + (size_t)(r0 + sr) * KDIM + sseg * 4;  // + kt*32
  const int ae = (sseg >> 1) * 64 + sr;   // dest entry (g = sseg>>1)
  const int ah = (sseg & 1) * 8;          // byte offset within entry

#define STAGE_B(buf, kt)                                                   \
  {                                                                        \
    _Pragma("unroll")                                                      \
    for (int s = 0; s < 4; ++s)                                            \
      gload_lds16(c1tH + (kt) * 2048 + s * 512 + tid,                      \
                  &Bs[buf][s * 512 + tid]);                                \
  }

  f32x4 acc[2][8];
  #pragma unroll
  for (int rf = 0; rf < 2; ++rf)
    #pragma unroll
    for (int cf = 0; cf < 8; ++cf)
      acc[rf][cf] = (f32x4){0.f, 0.f, 0.f, 0.f};

  // ---- prologue: stage A(0) (reg path) + B(0) (DMA) ----
  {
    const float4 a0 = *(const float4*)(xsrc);
    STAGE_B(0, 0);
    cvtstore4(a0, (char*)&As[0][ae] + ah);
  }
  __syncthreads();

  int cur = 0;
  #pragma unroll
  for (int kt = 0; kt < 16; ++kt) {
    // ---- phase top: issue next-phase loads (land during compute) ----
    float4 araw;
    if (kt < 15) {
      araw = *(const float4*)(xsrc + (kt + 1) * 32);
      STAGE_B(cur ^ 1, kt + 1);
    }
    // ---- compute kt: LDS only ----
    const int fa = g * 64 + wr * 32 + lr;
    const short8 A0 = As[cur][fa];
    const short8 A1 = As[cur][fa + 16];
    const int fb = g * 512 + wc * 128 + lr;
    {
      const short8 b0 = Bs[cur][fb];
      const short8 b1 = Bs[cur][fb + 16];
      const short8 b2 = Bs[cur][fb + 32];
      const short8 b3 = Bs[cur][fb + 48];
      acc[0][0] = __builtin_amdgcn_mfma_f32_16x16x32_bf16(A0, b0, acc[0][0], 0, 0, 0);
      acc[1][0] = __builtin_amdgcn_mfma_f32_16x16x32_bf16(A1, b0, acc[1][0], 0, 0, 0);
      acc[0][1] = __builtin_amdgcn_mfma_f32_16x16x32_bf16(A0, b1, acc[0][1], 0, 0, 0);
      acc[1][1] = __builtin_amdgcn_mfma_f32_16x16x32_bf16(A1, b1, acc[1][1], 0, 0, 0);
      acc[0][2] = __builtin_amdgcn_mfma_f32_16x16x32_bf16(A0, b2, acc[0][2], 0, 0, 0);
      acc[1][2] = __builtin_amdgcn_mfma_f32_16x16x32_bf16(A1, b2, acc[1][2], 0, 0, 0);
      acc[0][3] = __builtin_amdgcn_mfma_f32_16x16x32_bf16(A0, b3, acc[0][3], 0, 0, 0);
      acc[1][3] = __builtin_amdgcn_mfma_f32_16x16x32_bf16(A1, b3, acc[1][3], 0, 0, 0);
    }
    {
      const short8 b4 = Bs[cur][fb + 64];
      const short8 b5 = Bs[cur][fb + 80];
      const short8 b6 = Bs[cur][fb + 96];
      const short8 b7 = Bs[cur][fb + 112];
      acc[0][4] = __builtin_amdgcn_mfma_f32_16x16x32_bf16(A0, b4, acc[0][4], 0, 0, 0);
      acc[1][4] = __builtin_amdgcn_mfma_f32_16x16x32_bf16(A1, b4, acc[1][4], 0, 0, 0);
      acc[0][5] = __builtin_amdgcn_mfma_f32_16x16x32_bf16(A0, b5, acc[0][5], 0, 0, 0);
      acc[1][5] = __builtin_amdgcn_mfma_f32_16x16x32_bf16(A1, b5, acc[1][5], 0, 0, 0);
      acc[0][6] = __builtin_amdgcn_mfma_f32_16x16x32_bf16(A0, b6, acc[0][6], 0, 0, 0);
      acc[1][6] = __builtin_amdgcn_mfma_f32_16x16x32_bf16(A1, b6, acc[1][6], 0, 0, 0);
      acc[0][7] = __builtin_amdgcn_mfma_f32_16x16x32_bf16(A0, b7, acc[0][7], 0, 0, 0);
      acc[1][7] = __builtin_amdgcn_mfma_f32_16x16x32_bf16(A1, b7, acc[1][7], 0, 0, 0);
    }
    // ---- phase late: cvt + LDS-write the landed A tile (vmcnt(4) only) ----
    if (kt < 15) cvtstore4(araw, (char*)&As[cur ^ 1][ae] + ah);
    __syncthreads();
    cur ^= 1;
  }
#undef STAGE_B

  // ---- epilogue: row-dot against X for this wave's 128-col slice ----
  #pragma unroll
  for (int rf = 0; rf < 2; ++rf)
    #pragma unroll
    for (int p = 0; p < 4; ++p) {
      const int row = wr * 32 + rf * 16 + g * 4 + p;
      const float* xr = X + (size_t)(r0 + row) * KDIM + wc * 128;
      float s = 0.f;
      #pragma unroll
      for (int cf = 0; cf < 8; ++cf)
        s += acc[rf][cf][p] * xr[cf * 16 + lr];
      s += __shfl_xor(s, 1, 64);
      s += __shfl_xor(s, 2, 64);
      s += __shfl_xor(s, 4, 64);
      s += __shfl_xor(s, 8, 64);
      if (lr == 0) qPart[wc][row] = s;
    }
  __syncthreads();
  if (tid < BM) {
    const float q = qPart[0][tid] + qPart[1][tid] + qPart[2][tid] + qPart[3][tid];
    quad[r0 + tid] = q;
    qLds[tid] = q;
  }
  __syncthreads();
  // ---- fused column stats over the (cache-hot) X panel: 1 col per thread ----
  {
    float s1 = 0.f, s2 = 0.f, s3 = 0.f;
    for (int r = 0; r < BM; ++r) {
      const float q = qLds[r];
      const float x = X[(size_t)(r0 + r) * KDIM + tid];
      s1 += x; s2 += x * x; s3 += q * x;
    }
    atomicAdd(&colS1[tid], s1);
    atomicAdd(&colS2[tid], s2);
    atomicAdd(&colS3[tid], s3);
  }
  if (tid < BM) {   // one full wave: reduce q, q^2 across 64 lanes
    double q = (double)qLds[tid];
    double q2 = q * q;
    #pragma unroll
    for (int m = 1; m < 64; m <<= 1) {
      q  += __shfl_xor(q,  m, 64);
      q2 += __shfl_xor(q2, m, 64);
    }
    if (tid == 0) { atomicAdd(&qsums[0], q); atomicAdd(&qsums[1], q2); }
  }
}

// ---------------- finalize per-feature mean / inv_std ----------------
__global__ void finalize_kernel(const float* __restrict__ colS1, const float* __restrict__ colS2,
                                const float* __restrict__ colS3, const double* __restrict__ qsums,
                                const float* __restrict__ C2, const float* __restrict__ C3,
                                float* __restrict__ mean, float* __restrict__ inv_std) {
  const int k = blockIdx.x * blockDim.x + threadIdx.x;
  if (k >= KDIM) return;
  const double invN = 1.0 / (double)NROWS;
  const double meanQ = qsums[0] * invN;
  const double varQ  = qsums[1] * invN - meanQ * meanQ;
  const float meanX = colS1[k] * (float)invN;
  const float varX  = colS2[k] * (float)invN - meanX * meanX;
  const float covQX = colS3[k] * (float)invN - (float)meanQ * meanX;
  const float c2 = C2[k];
  const float c3 = C3[0];
  const float m = (float)meanQ + c2 * meanX + c3;
  const float v = (float)varQ + c2 * c2 * varX + 2.0f * c2 * covQX;
  mean[k] = m;
  inv_std[k] = 1.0f / sqrtf(v + BN_EPS);
}

// ---------------- normalize + write ----------------
__global__ __launch_bounds__(256)
void normalize_kernel(const float* __restrict__ X, const float* __restrict__ quad,
                      const float* __restrict__ C2, const float* __restrict__ C3,
                      const float* __restrict__ mean, const float* __restrict__ inv_std,
                      float* __restrict__ out) {
  const int idx = blockIdx.x * blockDim.x + threadIdx.x;  // float4 index
  const int n = idx >> 7;
  const int j4 = idx & 127;
  const float q = quad[n];
  const float c3 = C3[0];
  const float4 x  = *(const float4*)&X[(size_t)idx * 4];
  const float4 c2 = *(const float4*)&C2[j4 * 4];
  const float4 m  = *(const float4*)&mean[j4 * 4];
  const float4 iv = *(const float4*)&inv_std[j4 * 4];
  float4 o;
  o.x = (q + c2.x * x.x + c3 - m.x) * iv.x;
  o.y = (q + c2.y * x.y + c3 - m.y) * iv.y;
  o.z = (q + c2.z * x.z + c3 - m.z) * iv.z;
  o.w = (q + c2.w * x.w + c3 - m.w) * iv.w;
  *(float4*)&out[(size_t)idx * 4] = o;
}

extern "C" void kernel_launch(void* const* d_in, const int* in_sizes, int n_in,
                              void* d_out, int out_size, void* d_ws, size_t ws_size,
                              hipStream_t stream) {
  const float* X  = (const float*)d_in[0];
  const float* C1 = (const float*)d_in[1];
  const float* C2 = (const float*)d_in[2];
  const float* C3 = (const float*)d_in[3];
  float* out = (float*)d_out;

  char* ws = (char*)d_ws;
  float*  quad    = (float*)ws;                                        // 256 KB
  float*  colS1   = (float*)(ws + (size_t)NROWS * 4);                  // K
  float*  colS2   = colS1 + KDIM;
  float*  colS3   = colS2 + KDIM;
  double* qsums   = (double*)(ws + (size_t)NROWS * 4 + 3 * KDIM * 4);  // 2 doubles
  float*  mean    = (float*)(ws + (size_t)NROWS * 4 + 3 * KDIM * 4 + 16);
  float*  inv_std = mean + KDIM;
  short8* c1tH    = (short8*)(ws + 276480);                            // 512 KB (16B aligned)

  hipMemsetAsync(colS1, 0, 3 * KDIM * 4 + 16, stream);

  prep_c1<<<128, 256, 0, stream>>>(C1, c1tH);
  quad_kernel<<<NROWS / BM, 512, 0, stream>>>(X, c1tH, quad,
                                              colS1, colS2, colS3, qsums);
  finalize_kernel<<<2, 256, 0, stream>>>(colS1, colS2, colS3, qsums, C2, C3, mean, inv_std);
  normalize_kernel<<<(NROWS * (KDIM / 4)) / 256, 256, 0, stream>>>(
      X, quad, C2, C3, mean, inv_std, out);
}

// Round 16
// 131.878 us; speedup vs baseline: 1.4336x; 1.1220x over previous
//
#include <hip/hip_runtime.h>

#define NROWS 65536
#define KDIM  512
constexpr float BN_EPS = 1e-5f;

using short8 = __attribute__((ext_vector_type(8))) short;
using f32x4  = __attribute__((ext_vector_type(4))) float;

#define BM 64

// async global->LDS, 16B per lane
__device__ __forceinline__ void gload_lds16(const void* g, void* l) {
  __builtin_amdgcn_global_load_lds(
      (const __attribute__((address_space(1))) void*)g,
      (__attribute__((address_space(3))) void*)l, 16, 0, 0);
}

// RNE fp32 -> bf16: convert 4 floats, store as 8 bytes (ds_write_b64)
__device__ __forceinline__ void cvtstore4(const float4 a, void* dst) {
  unsigned u0 = __float_as_uint(a.x); u0 += 0x7FFFu + ((u0 >> 16) & 1u);
  unsigned u1 = __float_as_uint(a.y); u1 += 0x7FFFu + ((u1 >> 16) & 1u);
  unsigned u2 = __float_as_uint(a.z); u2 += 0x7FFFu + ((u2 >> 16) & 1u);
  unsigned u3 = __float_as_uint(a.w); u3 += 0x7FFFu + ((u3 >> 16) & 1u);
  int2 p;
  p.x = (int)((u0 >> 16) | (u1 & 0xFFFF0000u));
  p.y = (int)((u2 >> 16) | (u3 & 0xFFFF0000u));
  *(int2*)dst = p;
}

// ---------------- prep: C1 -> fragment-tiled bf16 (RNE) ----------------
// entry e = kg*512 + col holds C1[kg*8 + i][col], i=0..7 (one B-fragment).
__global__ __launch_bounds__(256)
void prep_c1(const float* __restrict__ C1, short8* __restrict__ c1tH) {
  const int e   = blockIdx.x * 256 + threadIdx.x;   // 0..32767
  const int col = e & 511;
  const int kg  = e >> 9;
  short8 hi;
  #pragma unroll
  for (int i = 0; i < 8; ++i) {
    const float x = C1[(size_t)(kg * 8 + i) * KDIM + col];   // coalesced
    unsigned u = __float_as_uint(x);
    u += 0x7FFFu + ((u >> 16) & 1u);
    hi[i] = (short)(u >> 16);
  }
  c1tH[e] = hi;
}

// ---------------- quad: pure LDS+MFMA loop, A reg-staged in-loop ----------------
// quad[n] = x_n^T C1 x_n (1-pass bf16 MFMA), fused column stats.
// 8 waves = 2 row-groups x 4 col-groups (wave tile 32 rows x 128 cols).
// Per kt phase: (top) issue 1 coalesced float4 X-load per thread (A tile
// for kt+1) + the 32 KB B-DMA (global_load_lds, dbuf); (middle) compute kt
// purely from LDS; (late) cvt the landed X float4 -> bf16, ds_write_b64.
// __launch_bounds__(512, 4): r15 post-mortem — VGPR 68 + AGPR 64 = 132
// crossed the 128-reg occupancy cliff (2 waves/SIMD, 22% occ). The cap
// asks the allocator to shave ~4 regs (remat range) so 2 blocks/CU
// co-reside at 4 waves/SIMD. NEVER cap below the live set (r6/r10) —
// here the cap is 128 vs live ~132.
__global__ __launch_bounds__(512, 4)
void quad_kernel(const float* __restrict__ X, const short8* __restrict__ c1tH,
                 float* __restrict__ quad,
                 float* __restrict__ colS1, float* __restrict__ colS2,
                 float* __restrict__ colS3, double* __restrict__ qsums) {
  __shared__ short8 Bs[2][2048];      // 2 x 32 KB
  __shared__ short8 As[2][256];       // 2 x 4 KB  (entry g*64+row = X[row][kt*32+g*8..+7])
  __shared__ float qPart[4][BM];
  __shared__ float qLds[BM];

  const int tid  = threadIdx.x;
  const int lane = tid & 63;
  const int w    = tid >> 6;          // wave 0..7
  const int wr   = w >> 2;            // row-group (0..1): rows wr*32..+31
  const int wc   = w & 3;             // col-group (0..3): cols wc*128..+127
  const int g    = lane >> 4;         // k-group 0..3
  const int lr   = lane & 15;
  const int r0   = blockIdx.x * BM;

  // ---- A staging assignment: thread -> (row, float4-segment) ----
  const int sr   = tid >> 3;          // row 0..63
  const int sseg = tid & 7;           // 4-float segment 0..7 of the 32-k slice
  const float* xsrc = X + (size_t)(r0 + sr) * KDIM + sseg * 4;  // + kt*32
  const int ae = (sseg >> 1) * 64 + sr;   // dest entry (g = sseg>>1)
  const int ah = (sseg & 1) * 8;          // byte offset within entry

#define STAGE_B(buf, kt)                                                   \
  {                                                                        \
    _Pragma("unroll")                                                      \
    for (int s = 0; s < 4; ++s)                                            \
      gload_lds16(c1tH + (kt) * 2048 + s * 512 + tid,                      \
                  &Bs[buf][s * 512 + tid]);                                \
  }

  f32x4 acc[2][8];
  #pragma unroll
  for (int rf = 0; rf < 2; ++rf)
    #pragma unroll
    for (int cf = 0; cf < 8; ++cf)
      acc[rf][cf] = (f32x4){0.f, 0.f, 0.f, 0.f};

  // ---- prologue: stage A(0) (reg path) + B(0) (DMA) ----
  {
    const float4 a0 = *(const float4*)(xsrc);
    STAGE_B(0, 0);
    cvtstore4(a0, (char*)&As[0][ae] + ah);
  }
  __syncthreads();

  int cur = 0;
  #pragma unroll
  for (int kt = 0; kt < 16; ++kt) {
    // ---- phase top: issue next-phase loads (land during compute) ----
    float4 araw;
    if (kt < 15) {
      araw = *(const float4*)(xsrc + (kt + 1) * 32);
      STAGE_B(cur ^ 1, kt + 1);
    }
    // ---- compute kt: LDS only ----
    const int fa = g * 64 + wr * 32 + lr;
    const short8 A0 = As[cur][fa];
    const short8 A1 = As[cur][fa + 16];
    const int fb = g * 512 + wc * 128 + lr;
    {
      const short8 b0 = Bs[cur][fb];
      const short8 b1 = Bs[cur][fb + 16];
      const short8 b2 = Bs[cur][fb + 32];
      const short8 b3 = Bs[cur][fb + 48];
      acc[0][0] = __builtin_amdgcn_mfma_f32_16x16x32_bf16(A0, b0, acc[0][0], 0, 0, 0);
      acc[1][0] = __builtin_amdgcn_mfma_f32_16x16x32_bf16(A1, b0, acc[1][0], 0, 0, 0);
      acc[0][1] = __builtin_amdgcn_mfma_f32_16x16x32_bf16(A0, b1, acc[0][1], 0, 0, 0);
      acc[1][1] = __builtin_amdgcn_mfma_f32_16x16x32_bf16(A1, b1, acc[1][1], 0, 0, 0);
      acc[0][2] = __builtin_amdgcn_mfma_f32_16x16x32_bf16(A0, b2, acc[0][2], 0, 0, 0);
      acc[1][2] = __builtin_amdgcn_mfma_f32_16x16x32_bf16(A1, b2, acc[1][2], 0, 0, 0);
      acc[0][3] = __builtin_amdgcn_mfma_f32_16x16x32_bf16(A0, b3, acc[0][3], 0, 0, 0);
      acc[1][3] = __builtin_amdgcn_mfma_f32_16x16x32_bf16(A1, b3, acc[1][3], 0, 0, 0);
    }
    {
      const short8 b4 = Bs[cur][fb + 64];
      const short8 b5 = Bs[cur][fb + 80];
      const short8 b6 = Bs[cur][fb + 96];
      const short8 b7 = Bs[cur][fb + 112];
      acc[0][4] = __builtin_amdgcn_mfma_f32_16x16x32_bf16(A0, b4, acc[0][4], 0, 0, 0);
      acc[1][4] = __builtin_amdgcn_mfma_f32_16x16x32_bf16(A1, b4, acc[1][4], 0, 0, 0);
      acc[0][5] = __builtin_amdgcn_mfma_f32_16x16x32_bf16(A0, b5, acc[0][5], 0, 0, 0);
      acc[1][5] = __builtin_amdgcn_mfma_f32_16x16x32_bf16(A1, b5, acc[1][5], 0, 0, 0);
      acc[0][6] = __builtin_amdgcn_mfma_f32_16x16x32_bf16(A0, b6, acc[0][6], 0, 0, 0);
      acc[1][6] = __builtin_amdgcn_mfma_f32_16x16x32_bf16(A1, b6, acc[1][6], 0, 0, 0);
      acc[0][7] = __builtin_amdgcn_mfma_f32_16x16x32_bf16(A0, b7, acc[0][7], 0, 0, 0);
      acc[1][7] = __builtin_amdgcn_mfma_f32_16x16x32_bf16(A1, b7, acc[1][7], 0, 0, 0);
    }
    // ---- phase late: cvt + LDS-write the landed A tile (vmcnt(4) only) ----
    if (kt < 15) cvtstore4(araw, (char*)&As[cur ^ 1][ae] + ah);
    __syncthreads();
    cur ^= 1;
  }
#undef STAGE_B

  // ---- epilogue: row-dot against X for this wave's 128-col slice ----
  #pragma unroll
  for (int rf = 0; rf < 2; ++rf)
    #pragma unroll
    for (int p = 0; p < 4; ++p) {
      const int row = wr * 32 + rf * 16 + g * 4 + p;
      const float* xr = X + (size_t)(r0 + row) * KDIM + wc * 128;
      float s = 0.f;
      #pragma unroll
      for (int cf = 0; cf < 8; ++cf)
        s += acc[rf][cf][p] * xr[cf * 16 + lr];
      s += __shfl_xor(s, 1, 64);
      s += __shfl_xor(s, 2, 64);
      s += __shfl_xor(s, 4, 64);
      s += __shfl_xor(s, 8, 64);
      if (lr == 0) qPart[wc][row] = s;
    }
  __syncthreads();
  if (tid < BM) {
    const float q = qPart[0][tid] + qPart[1][tid] + qPart[2][tid] + qPart[3][tid];
    quad[r0 + tid] = q;
    qLds[tid] = q;
  }
  __syncthreads();
  // ---- fused column stats over the (cache-hot) X panel: 1 col per thread ----
  {
    float s1 = 0.f, s2 = 0.f, s3 = 0.f;
    for (int r = 0; r < BM; ++r) {
      const float q = qLds[r];
      const float x = X[(size_t)(r0 + r) * KDIM + tid];
      s1 += x; s2 += x * x; s3 += q * x;
    }
    atomicAdd(&colS1[tid], s1);
    atomicAdd(&colS2[tid], s2);
    atomicAdd(&colS3[tid], s3);
  }
  if (tid < BM) {   // one full wave: reduce q, q^2 across 64 lanes
    double q = (double)qLds[tid];
    double q2 = q * q;
    #pragma unroll
    for (int m = 1; m < 64; m <<= 1) {
      q  += __shfl_xor(q,  m, 64);
      q2 += __shfl_xor(q2, m, 64);
    }
    if (tid == 0) { atomicAdd(&qsums[0], q); atomicAdd(&qsums[1], q2); }
  }
}

// ---------------- finalize per-feature mean / inv_std ----------------
__global__ void finalize_kernel(const float* __restrict__ colS1, const float* __restrict__ colS2,
                                const float* __restrict__ colS3, const double* __restrict__ qsums,
                                const float* __restrict__ C2, const float* __restrict__ C3,
                                float* __restrict__ mean, float* __restrict__ inv_std) {
  const int k = blockIdx.x * blockDim.x + threadIdx.x;
  if (k >= KDIM) return;
  const double invN = 1.0 / (double)NROWS;
  const double meanQ = qsums[0] * invN;
  const double varQ  = qsums[1] * invN - meanQ * meanQ;
  const float meanX = colS1[k] * (float)invN;
  const float varX  = colS2[k] * (float)invN - meanX * meanX;
  const float covQX = colS3[k] * (float)invN - (float)meanQ * meanX;
  const float c2 = C2[k];
  const float c3 = C3[0];
  const float m = (float)meanQ + c2 * meanX + c3;
  const float v = (float)varQ + c2 * c2 * varX + 2.0f * c2 * covQX;
  mean[k] = m;
  inv_std[k] = 1.0f / sqrtf(v + BN_EPS);
}

// ---------------- normalize + write ----------------
__global__ __launch_bounds__(256)
void normalize_kernel(const float* __restrict__ X, const float* __restrict__ quad,
                      const float* __restrict__ C2, const float* __restrict__ C3,
                      const float* __restrict__ mean, const float* __restrict__ inv_std,
                      float* __restrict__ out) {
  const int idx = blockIdx.x * blockDim.x + threadIdx.x;  // float4 index
  const int n = idx >> 7;
  const int j4 = idx & 127;
  const float q = quad[n];
  const float c3 = C3[0];
  const float4 x  = *(const float4*)&X[(size_t)idx * 4];
  const float4 c2 = *(const float4*)&C2[j4 * 4];
  const float4 m  = *(const float4*)&mean[j4 * 4];
  const float4 iv = *(const float4*)&inv_std[j4 * 4];
  float4 o;
  o.x = (q + c2.x * x.x + c3 - m.x) * iv.x;
  o.y = (q + c2.y * x.y + c3 - m.y) * iv.y;
  o.z = (q + c2.z * x.z + c3 - m.z) * iv.z;
  o.w = (q + c2.w * x.w + c3 - m.w) * iv.w;
  *(float4*)&out[(size_t)idx * 4] = o;
}

extern "C" void kernel_launch(void* const* d_in, const int* in_sizes, int n_in,
                              void* d_out, int out_size, void* d_ws, size_t ws_size,
                              hipStream_t stream) {
  const float* X  = (const float*)d_in[0];
  const float* C1 = (const float*)d_in[1];
  const float* C2 = (const float*)d_in[2];
  const float* C3 = (const float*)d_in[3];
  float* out = (float*)d_out;

  char* ws = (char*)d_ws;
  float*  quad    = (float*)ws;                                        // 256 KB
  float*  colS1   = (float*)(ws + (size_t)NROWS * 4);                  // K
  float*  colS2   = colS1 + KDIM;
  float*  colS3   = colS2 + KDIM;
  double* qsums   = (double*)(ws + (size_t)NROWS * 4 + 3 * KDIM * 4);  // 2 doubles
  float*  mean    = (float*)(ws + (size_t)NROWS * 4 + 3 * KDIM * 4 + 16);
  float*  inv_std = mean + KDIM;
  short8* c1tH    = (short8*)(ws + 276480);                            // 512 KB (16B aligned)

  hipMemsetAsync(colS1, 0, 3 * KDIM * 4 + 16, stream);

  prep_c1<<<128, 256, 0, stream>>>(C1, c1tH);
  quad_kernel<<<NROWS / BM, 512, 0, stream>>>(X, c1tH, quad,
                                              colS1, colS2, colS3, qsums);
  finalize_kernel<<<2, 256, 0, stream>>>(colS1, colS2, colS3, qsums, C2, C3, mean, inv_std);
  normalize_kernel<<<(NROWS * (KDIM / 4)) / 256, 256, 0, stream>>>(
      X, quad, C2, C3, mean, inv_std, out);
}